// Round 10
// baseline (240.813 us; speedup 1.0000x reference)
//
#include <hip/hip_runtime.h>

// Integrate-and-fire forward: x (T=32, B=16, N=65536) fp32 -> y same shape.
// Per neuron: m = v + x[t]; y = (m >= 1) ? 1 : 0; v = m - y  (soft reset).
// Parallel over B*N neurons; sequential T-loop in registers. Memory-bound:
// 256 MiB traffic; mixed-stream floor ~43 us at 6.3 TB/s (d2d copy ref),
// harness fill does 6.7 TB/s write-only with PLAIN stores.
//
// Ladder: r1 float4 no-PF plain = 120 us. r8 f32x2+PF4+nt = ~74 us.
// r9 PF8+CT-shape = neutral -> MLP saturated, not the limiter.
// r10 changes (store-path attack):
//  - stores PLAIN (drop nt: suspect streaming-write path is slower than the
//    L2 write-combine path the 6.7 TB/s fill uses); loads keep nt
//  - batch-8 double-buffer: {load 8 t's} -> {compute+store 8} so the DRAM bus
//    sees direction-coherent bursts instead of 1-load-1-store interleave

#define T_STEPS 32
#define BATCH 8
#define NBATCH (T_STEPS / BATCH)

typedef float f32x2 __attribute__((ext_vector_type(2)));

template <int BN2_CT>
__global__ __launch_bounds__(256) void if_fwd_kernel(const f32x2* __restrict__ x,
                                                     f32x2* __restrict__ y,
                                                     int bn2_rt) {
    const int bn2 = (BN2_CT > 0) ? BN2_CT : bn2_rt;
    const int i = blockIdx.x * blockDim.x + threadIdx.x;
    if (i >= bn2) return;

    const f32x2* xp = x + i;
    f32x2* yp = y + i;

    // Double-buffered batches; all indices compile-time after full unroll.
    f32x2 buf[2][BATCH];

#pragma unroll
    for (int j = 0; j < BATCH; ++j)
        buf[0][j] = __builtin_nontemporal_load(&xp[(size_t)j * (size_t)bn2]);

    float vx = 0.f, vy = 0.f;

#pragma unroll
    for (int kb = 0; kb < NBATCH; ++kb) {
        const int cur = kb & 1;
        const int nxt = cur ^ 1;

        // Burst-issue next batch's 8 loads before consuming current batch.
        if (kb + 1 < NBATCH) {
#pragma unroll
            for (int j = 0; j < BATCH; ++j)
                buf[nxt][j] = __builtin_nontemporal_load(
                    &xp[(size_t)((kb + 1) * BATCH + j) * (size_t)bn2]);
        }

        // Compute the sequential recurrence and burst-store 8 results (plain).
#pragma unroll
        for (int j = 0; j < BATCH; ++j) {
            f32x2 xt = buf[cur][j];
            float mx = vx + xt.x;
            float my = vy + xt.y;
            float sx = (mx >= 1.0f) ? 1.0f : 0.0f;
            float sy = (my >= 1.0f) ? 1.0f : 0.0f;
            vx = mx - sx;
            vy = my - sy;
            f32x2 s;
            s.x = sx;
            s.y = sy;
            yp[(size_t)(kb * BATCH + j) * (size_t)bn2] = s;  // plain store
        }
    }
}

extern "C" void kernel_launch(void* const* d_in, const int* in_sizes, int n_in,
                              void* d_out, int out_size, void* d_ws, size_t ws_size,
                              hipStream_t stream) {
    const float* x = (const float*)d_in[0];
    float* y = (float*)d_out;

    const int total = in_sizes[0];      // T*B*N
    const int bn = total / T_STEPS;     // neurons
    const int bn2 = bn / 2;             // f32x2 lanes

    const int block = 256;
    const int grid = (bn2 + block - 1) / block;  // 2048 WGs -> 8 WG/CU

    constexpr int kBN2 = (32 * 16 * 65536 / 32) / 2;  // 524288 for the bench shape
    if (bn2 == kBN2) {
        if_fwd_kernel<kBN2><<<grid, block, 0, stream>>>((const f32x2*)x, (f32x2*)y, bn2);
    } else {
        if_fwd_kernel<0><<<grid, block, 0, stream>>>((const f32x2*)x, (f32x2*)y, bn2);
    }
}

// Round 12
// 238.994 us; speedup vs baseline: 1.0076x; 1.0076x over previous
//
#include <hip/hip_runtime.h>

// Integrate-and-fire forward: x (T=32, B=16, N=65536) fp32 -> y same shape.
// Per neuron: m = v + x[t]; y = (m >= 1) ? 1 : 0; v = m - y  (soft reset).
// Parallel over B*N neurons; sequential T-loop in registers. Memory-bound:
// 256 MiB logical traffic; tuned mixed-stream floor ~43 us (m13 6.3 TB/s),
// harness d2d copy only manages 3.3 TB/s logical (81 us) - we beat it already.
//
// Ladder: r1 float4 noPF = 120us | r8 f32x2+PF4+nt(ld+st) = ~74us |
// r9 +PF8+CTshape = neutral (MLP saturated) | r10 plain-st+batch8 = REGRESS
// (confounded; batch8 buf[2][8] suspected scratch spill, rule #20).
// r11: r9 base, SINGLE change = stores plain (keep nt loads).
// Theory: stores share vmcnt with loads; nt stores ack at HBM (slow retire ->
// every load-wait transitively stalls on old stores), plain stores ack at L2
// where d_out's poison-dirty lines already sit. The 6.7 TB/s fill is plain.

#define T_STEPS 32
#define PF 8  // prefetch depth (outstanding loads per wave)

typedef float f32x2 __attribute__((ext_vector_type(2)));

template <int BN2_CT>
__global__ __launch_bounds__(256) void if_fwd_kernel(const f32x2* __restrict__ x,
                                                     f32x2* __restrict__ y,
                                                     int bn2_rt) {
    const int bn2 = (BN2_CT > 0) ? BN2_CT : bn2_rt;
    const int i = blockIdx.x * blockDim.x + threadIdx.x;
    if (i >= bn2) return;

    // Prime the pipeline: PF loads in flight before any compute.
    f32x2 buf[PF];
#pragma unroll
    for (int t = 0; t < PF; ++t)
        buf[t] = __builtin_nontemporal_load(&x[(size_t)t * (size_t)bn2 + (size_t)i]);

    float vx = 0.f, vy = 0.f;

#pragma unroll
    for (int t = 0; t < T_STEPS; ++t) {
        f32x2 xt = buf[t % PF];  // compile-time index after full unroll

        // Issue the t+PF load before consuming t: keeps PF loads outstanding.
        if (t + PF < T_STEPS)
            buf[(t + PF) % PF] =
                __builtin_nontemporal_load(&x[(size_t)(t + PF) * (size_t)bn2 + (size_t)i]);

        float mx = vx + xt.x;
        float my = vy + xt.y;
        float sx = (mx >= 1.0f) ? 1.0f : 0.0f;
        float sy = (my >= 1.0f) ? 1.0f : 0.0f;
        vx = mx - sx;
        vy = my - sy;

        f32x2 s;
        s.x = sx;
        s.y = sy;
        y[(size_t)t * (size_t)bn2 + (size_t)i] = s;  // PLAIN store (r11 change)
    }
}

extern "C" void kernel_launch(void* const* d_in, const int* in_sizes, int n_in,
                              void* d_out, int out_size, void* d_ws, size_t ws_size,
                              hipStream_t stream) {
    const float* x = (const float*)d_in[0];
    float* y = (float*)d_out;

    const int total = in_sizes[0];      // T*B*N
    const int bn = total / T_STEPS;     // neurons
    const int bn2 = bn / 2;             // f32x2 lanes

    const int block = 256;
    const int grid = (bn2 + block - 1) / block;  // 2048 WGs -> 8 WG/CU

    constexpr int kBN2 = (32 * 16 * 65536 / 32) / 2;  // 524288 for the bench shape
    if (bn2 == kBN2) {
        if_fwd_kernel<kBN2><<<grid, block, 0, stream>>>((const f32x2*)x, (f32x2*)y, bn2);
    } else {
        if_fwd_kernel<0><<<grid, block, 0, stream>>>((const f32x2*)x, (f32x2*)y, bn2);
    }
}

// Round 16
// 223.699 us; speedup vs baseline: 1.0765x; 1.0684x over previous
//
#include <hip/hip_runtime.h>

// Integrate-and-fire forward: x (T=32, B=16, N=65536) fp32 -> y same shape.
// Per neuron: m = v + x[t]; y = (m >= 1) ? 1 : 0; v = m - y  (soft reset).
// Parallel over B*N neurons; sequential T-loop in registers. Memory-bound:
// 256 MiB logical traffic; mixed-stream floor ~43 us (m13: 6.3 TB/s float4 copy).
//
// Ladder: r1 float4 noPF plain = 120us | r8 f32x2+PF4+nt = ~74us |
// r9 PF8+CTshape = neutral (MLP saturated) | r10/r12 plain stores = +13us
// REGRESS (plain stores allocate in L2 -> y-stream thrashes 32MiB L2, evicts
// the ~half-L3-resident x; nt stores bypass. Fill@6.7TB/s is write-only so
// doesn't see it). r13: SINGLE change vs r9 = width f32x2 -> f32x4, PF4.
// 1024 WGs x 256 = 16 waves/CU (50% cap) is fine: PF4 x 4KB x 16 = 256KB/CU
// in flight vs ~10KB needed; r1's float4 loss was no-PF serial chains.

#define T_STEPS 32
#define PF 4  // prefetch depth (outstanding loads per wave)

typedef float f32x4 __attribute__((ext_vector_type(4)));

template <int BN4_CT>
__global__ __launch_bounds__(256) void if_fwd_kernel(const f32x4* __restrict__ x,
                                                     f32x4* __restrict__ y,
                                                     int bn4_rt) {
    const int bn4 = (BN4_CT > 0) ? BN4_CT : bn4_rt;
    const int i = blockIdx.x * blockDim.x + threadIdx.x;
    if (i >= bn4) return;

    // Prime the pipeline: PF loads in flight before any compute.
    f32x4 buf[PF];
#pragma unroll
    for (int t = 0; t < PF; ++t)
        buf[t] = __builtin_nontemporal_load(&x[(size_t)t * (size_t)bn4 + (size_t)i]);

    f32x4 v = {0.f, 0.f, 0.f, 0.f};

#pragma unroll
    for (int t = 0; t < T_STEPS; ++t) {
        f32x4 xt = buf[t % PF];  // compile-time index after full unroll

        // Issue the t+PF load before consuming t: keeps PF loads outstanding.
        if (t + PF < T_STEPS)
            buf[(t + PF) % PF] =
                __builtin_nontemporal_load(&x[(size_t)(t + PF) * (size_t)bn4 + (size_t)i]);

        f32x4 m = v + xt;
        f32x4 s;
        s.x = (m.x >= 1.0f) ? 1.0f : 0.0f;
        s.y = (m.y >= 1.0f) ? 1.0f : 0.0f;
        s.z = (m.z >= 1.0f) ? 1.0f : 0.0f;
        s.w = (m.w >= 1.0f) ? 1.0f : 0.0f;
        v = m - s;

        __builtin_nontemporal_store(s, &y[(size_t)t * (size_t)bn4 + (size_t)i]);
    }
}

extern "C" void kernel_launch(void* const* d_in, const int* in_sizes, int n_in,
                              void* d_out, int out_size, void* d_ws, size_t ws_size,
                              hipStream_t stream) {
    const float* x = (const float*)d_in[0];
    float* y = (float*)d_out;

    const int total = in_sizes[0];      // T*B*N
    const int bn = total / T_STEPS;     // neurons
    const int bn4 = bn / 4;             // f32x4 lanes

    const int block = 256;
    const int grid = (bn4 + block - 1) / block;  // 1024 WGs -> 4 WG/CU, 16 waves/CU

    constexpr int kBN4 = (32 * 16 * 65536 / 32) / 4;  // 262144 for the bench shape
    if (bn4 == kBN4) {
        if_fwd_kernel<kBN4><<<grid, block, 0, stream>>>((const f32x4*)x, (f32x4*)y, bn4);
    } else {
        if_fwd_kernel<0><<<grid, block, 0, stream>>>((const f32x4*)x, (f32x4*)y, bn4);
    }
}